// Round 1
// 487.942 us; speedup vs baseline: 1.0364x; 1.0364x over previous
//
#include <hip/hip_runtime.h>
#include <math.h>

// ---------------------------------------------------------------------------
// DecoderLayer fused implementation (MI355X / gfx950)
//   K0: convert weights fp32 -> bf16 into ws (layouts already [n][k] row-major)
//   K1: per-node message MLP (3 GEMMs via mfma_f32_16x16x32_bf16) + edge-sum + LN1
//       -- phase 1 now uses T14 reg-staged double buffering (issue-early /
//          write-late), W1-fragment prefetch before the barrier, aligned
//          LDS stride (88 bf16 = 176 B, 16B-aligned, 2-way banks), and
//          v_cvt_pk_bf16_f32 for fp32->bf16 staging.
//   K2: FFN (128->512->128) + LN2 + mask_V
// ---------------------------------------------------------------------------

typedef __bf16 bf16;
typedef __attribute__((ext_vector_type(8))) __bf16 bf16x8;
typedef __attribute__((ext_vector_type(4))) __bf16 bf16x4;
typedef __attribute__((ext_vector_type(4))) float f32x4;

__device__ __forceinline__ bf16 f2bf(float f) {
    unsigned u = __builtin_bit_cast(unsigned, f);
    u += 0x7FFFu + ((u >> 16) & 1u);           // RTNE
    unsigned short s = (unsigned short)(u >> 16);
    return __builtin_bit_cast(bf16, s);
}

// pack two fp32 -> two bf16 (RTNE), one instruction
__device__ __forceinline__ unsigned cvt_pk_bf16(float lo, float hi) {
    unsigned r;
    asm("v_cvt_pk_bf16_f32 %0, %1, %2" : "=v"(r) : "v"(lo), "v"(hi));
    return r;
}

__device__ __forceinline__ float gelu_exact(float x) {
    return 0.5f * x * (1.0f + erff(x * 0.70710678118654752f));
}

__device__ __forceinline__ f32x4 mfma16(bf16x8 a, bf16x8 b, f32x4 c) {
    return __builtin_amdgcn_mfma_f32_16x16x32_bf16(a, b, c, 0, 0, 0);
}

// ws layout (bf16 elements unless noted):
//   W1b  @ 0       : 128*512 = 65536
//   W2b  @ 65536   : 128*128 = 16384
//   W3b  @ 81920   : 128*128 = 16384
//   Winb @ 98304   : 512*128 = 65536
//   Woutb@ 163840  : 128*512 = 65536   (total 229376 bf16 = 458752 B)
//   h1   @ byte 458752 : 4096*128 fp32 = 2 MB
#define WS_W2   65536
#define WS_W3   81920
#define WS_WIN  98304
#define WS_WOUT 163840
#define WS_TOTAL_W 229376
#define WS_H1_BYTES 458752

// ---------------------------------------------------------------------------
__global__ void convert_weights(const float* __restrict__ W1, const float* __restrict__ W2,
                                const float* __restrict__ W3, const float* __restrict__ Win,
                                const float* __restrict__ Wout, bf16* __restrict__ ws) {
    int i = blockIdx.x * 256 + threadIdx.x;
    if (i < WS_W2)              ws[i] = f2bf(W1[i]);
    else if (i < WS_W3)         ws[i] = f2bf(W2[i - WS_W2]);
    else if (i < WS_WIN)        ws[i] = f2bf(W3[i - WS_W3]);
    else if (i < WS_WOUT)       ws[i] = f2bf(Win[i - WS_WIN]);
    else if (i < WS_TOTAL_W)    ws[i] = f2bf(Wout[i - WS_WOUT]);
}

// ---------------------------------------------------------------------------
// K1: 2 nodes per block (M = 96 rows), 256 threads (4 waves).
//   phase1: X[96,512] @ W1^T -> gelu -> m1 (LDS)     K chunks of 64, dbuf'd in regs
//   phase2: m1 @ W2^T -> gelu -> m2 (LDS, aliases staging buf)
//   phase3: m2 @ W3^T -> +b3, *mask_attend, sum over edges, /30, +h_V, LN1 -> h1
__global__ __launch_bounds__(256, 3)
void msg_kernel(const float* __restrict__ h_V, const float* __restrict__ h_E,
                const float* __restrict__ mask_attend,
                const bf16* __restrict__ W1b, const bf16* __restrict__ W2b,
                const bf16* __restrict__ W3b,
                const float* __restrict__ b1, const float* __restrict__ b2,
                const float* __restrict__ b3,
                const float* __restrict__ ln1g, const float* __restrict__ ln1b,
                float* __restrict__ h1out) {
    __shared__ __align__(16) char smem[53248];
    bf16*  a_lds = (bf16*)smem;            // 96 x 88  = 16896 B   (phase1 staging)
    bf16*  m2    = (bf16*)smem;            // 96 x (128+8) = 26112 B (aliases a_lds)
    bf16*  m1    = (bf16*)(smem + 26112);  // 96 x (128+8) = 26112 B
    float* tbuf  = (float*)(smem + 52224); // 2 x 128 fp32 = 1024 B

    const int tid  = threadIdx.x;
    const int wave = tid >> 6;
    const int lane = tid & 63;
    const int q    = lane >> 4;     // quad 0..3
    const int c15  = lane & 15;
    const int g0   = blockIdx.x * 2;  // first node of this block

    f32x4 zero = {0.f, 0.f, 0.f, 0.f};
    f32x4 acc[6][2];
#pragma unroll
    for (int mt = 0; mt < 6; ++mt) { acc[mt][0] = zero; acc[mt][1] = zero; }

    // ---------------- phase 1 (T14 reg-staged double buffer) ----------------
    const int r0  = tid >> 4;   // staging row within 16-row group
    const int l16 = tid & 15;   // staging float4 index

#define STAGE_LOAD(dst, kb)                                                     \
    {                                                                           \
        const int cg_ = (kb) * 64 + l16 * 4;                                    \
        _Pragma("unroll")                                                       \
        for (int it = 0; it < 6; ++it) {                                        \
            const int row_ = it * 16 + r0;                                      \
            const int nl_  = row_ >= 48;                                        \
            const int g_   = g0 + nl_;                                          \
            const float* src_ = ((kb) < 2)                                      \
                ? (h_V + (size_t)g_ * 128 + cg_)                                \
                : (h_E + (size_t)(g_ * 48 + row_ - 48 * nl_) * 384 + (cg_ - 128)); \
            dst[it] = *(const float4*)src_;                                     \
        }                                                                       \
    }

#define STAGE_WRITE(src)                                                        \
    {                                                                           \
        _Pragma("unroll")                                                       \
        for (int it = 0; it < 6; ++it) {                                        \
            const int row_ = it * 16 + r0;                                      \
            uint2 w_;                                                           \
            w_.x = cvt_pk_bf16(src[it].x, src[it].y);                           \
            w_.y = cvt_pk_bf16(src[it].z, src[it].w);                           \
            *(uint2*)(a_lds + row_ * 88 + l16 * 4) = w_;                        \
        }                                                                       \
    }

    // One phase-1 step: issue next-tile global loads + this-tile W1 fragment
    // loads BEFORE the barrier (overlap with other waves' MFMA tail + our own
    // MFMA phase below), write staged regs late, then MFMA.
#define PH1_STEP(cur, nxt, kb, donext)                                          \
    {                                                                           \
        if (donext) STAGE_LOAD(nxt, (kb) + 1);                                  \
        bf16x8 bf0_[2], bf1_[2];                                                \
        _Pragma("unroll")                                                       \
        for (int s = 0; s < 2; ++s) {                                           \
            bf0_[s] = *(const bf16x8*)(W1b + (size_t)(wave * 32 + c15) * 512 + (kb) * 64 + s * 32 + q * 8);      \
            bf1_[s] = *(const bf16x8*)(W1b + (size_t)(wave * 32 + 16 + c15) * 512 + (kb) * 64 + s * 32 + q * 8); \
        }                                                                       \
        __syncthreads();              /* all waves done reading a_lds (kb-1) */ \
        STAGE_WRITE(cur);                                                       \
        __syncthreads();              /* staged tile visible */                 \
        __builtin_amdgcn_s_setprio(1);                                          \
        _Pragma("unroll")                                                       \
        for (int mt = 0; mt < 6; ++mt) {                                        \
            _Pragma("unroll")                                                   \
            for (int s = 0; s < 2; ++s) {                                       \
                bf16x8 af_ = *(const bf16x8*)(a_lds + (mt * 16 + c15) * 88 + s * 32 + q * 8); \
                acc[mt][0] = mfma16(af_, bf0_[s], acc[mt][0]);                  \
                acc[mt][1] = mfma16(af_, bf1_[s], acc[mt][1]);                  \
            }                                                                   \
        }                                                                       \
        __builtin_amdgcn_s_setprio(0);                                          \
    }

    {
        float4 rA[6], rB[6];
        STAGE_LOAD(rA, 0);
#pragma unroll 1
        for (int kb = 0; kb < 8; kb += 2) {
            PH1_STEP(rA, rB, kb, 1);
            PH1_STEP(rB, rA, kb + 1, (kb + 1) < 7);
        }
    }
#undef PH1_STEP
#undef STAGE_WRITE
#undef STAGE_LOAD

    // epilogue 1: bias + gelu -> m1   (C/D layout: row = q*4+reg, col = c15)
    {
        const float bb0 = b1[wave * 32 + c15];
        const float bb1 = b1[wave * 32 + 16 + c15];
#pragma unroll
        for (int mt = 0; mt < 6; ++mt) {
#pragma unroll
            for (int r = 0; r < 4; ++r) {
                const int row = mt * 16 + q * 4 + r;
                m1[row * 136 + wave * 32 + c15]      = f2bf(gelu_exact(acc[mt][0][r] + bb0));
                m1[row * 136 + wave * 32 + 16 + c15] = f2bf(gelu_exact(acc[mt][1][r] + bb1));
            }
        }
    }
    __syncthreads();

    // ---------------- phase 2 ----------------
#pragma unroll
    for (int mt = 0; mt < 6; ++mt) { acc[mt][0] = zero; acc[mt][1] = zero; }
    __builtin_amdgcn_s_setprio(1);
#pragma unroll
    for (int s = 0; s < 4; ++s) {
        const bf16x8 w0 = *(const bf16x8*)(W2b + (size_t)(wave * 32 + c15) * 128 + s * 32 + q * 8);
        const bf16x8 w1 = *(const bf16x8*)(W2b + (size_t)(wave * 32 + 16 + c15) * 128 + s * 32 + q * 8);
#pragma unroll
        for (int mt = 0; mt < 6; ++mt) {
            bf16x8 af = *(const bf16x8*)(m1 + (mt * 16 + c15) * 136 + s * 32 + q * 8);
            acc[mt][0] = mfma16(af, w0, acc[mt][0]);
            acc[mt][1] = mfma16(af, w1, acc[mt][1]);
        }
    }
    __builtin_amdgcn_s_setprio(0);
    {
        const float bb0 = b2[wave * 32 + c15];
        const float bb1 = b2[wave * 32 + 16 + c15];
#pragma unroll
        for (int mt = 0; mt < 6; ++mt) {
#pragma unroll
            for (int r = 0; r < 4; ++r) {
                const int row = mt * 16 + q * 4 + r;
                m2[row * 136 + wave * 32 + c15]      = f2bf(gelu_exact(acc[mt][0][r] + bb0));
                m2[row * 136 + wave * 32 + 16 + c15] = f2bf(gelu_exact(acc[mt][1][r] + bb1));
            }
        }
    }
    __syncthreads();

    // ---------------- phase 3 ----------------
#pragma unroll
    for (int mt = 0; mt < 6; ++mt) { acc[mt][0] = zero; acc[mt][1] = zero; }
    __builtin_amdgcn_s_setprio(1);
#pragma unroll
    for (int s = 0; s < 4; ++s) {
        const bf16x8 w0 = *(const bf16x8*)(W3b + (size_t)(wave * 32 + c15) * 128 + s * 32 + q * 8);
        const bf16x8 w1 = *(const bf16x8*)(W3b + (size_t)(wave * 32 + 16 + c15) * 128 + s * 32 + q * 8);
#pragma unroll
        for (int mt = 0; mt < 6; ++mt) {
            bf16x8 af = *(const bf16x8*)(m2 + (mt * 16 + c15) * 136 + s * 32 + q * 8);
            acc[mt][0] = mfma16(af, w0, acc[mt][0]);
            acc[mt][1] = mfma16(af, w1, acc[mt][1]);
        }
    }
    __builtin_amdgcn_s_setprio(0);
    // masked sum over edges
    {
        const float bb0 = b3[wave * 32 + c15];
        const float bb1 = b3[wave * 32 + 16 + c15];
        float s00 = 0.f, s01 = 0.f, s10 = 0.f, s11 = 0.f;
#pragma unroll
        for (int mt = 0; mt < 6; ++mt) {
#pragma unroll
            for (int r = 0; r < 4; ++r) {
                const int row = mt * 16 + q * 4 + r;
                const int nl  = row >= 48;
                const float mv = mask_attend[(size_t)(g0 + nl) * 48 + row - 48 * nl];
                const float v0 = (acc[mt][0][r] + bb0) * mv;
                const float v1 = (acc[mt][1][r] + bb1) * mv;
                if (nl) { s10 += v0; s11 += v1; } else { s00 += v0; s01 += v1; }
            }
        }
#pragma unroll
        for (int off = 16; off <= 32; off <<= 1) {
            s00 += __shfl_xor(s00, off);
            s01 += __shfl_xor(s01, off);
            s10 += __shfl_xor(s10, off);
            s11 += __shfl_xor(s11, off);
        }
        if (lane < 16) {
            const int col0 = wave * 32 + c15, col1 = col0 + 16;
            tbuf[col0]       = h_V[(size_t)g0 * 128 + col0]       + s00 * (1.0f / 30.0f);
            tbuf[col1]       = h_V[(size_t)g0 * 128 + col1]       + s01 * (1.0f / 30.0f);
            tbuf[128 + col0] = h_V[(size_t)(g0 + 1) * 128 + col0] + s10 * (1.0f / 30.0f);
            tbuf[128 + col1] = h_V[(size_t)(g0 + 1) * 128 + col1] + s11 * (1.0f / 30.0f);
        }
    }
    __syncthreads();
    // LN1: wave 0 -> node0, wave 1 -> node1
    if (wave < 2) {
        const float x0 = tbuf[wave * 128 + lane];
        const float x1 = tbuf[wave * 128 + 64 + lane];
        float sm = x0 + x1, sq = x0 * x0 + x1 * x1;
#pragma unroll
        for (int off = 1; off < 64; off <<= 1) { sm += __shfl_xor(sm, off); sq += __shfl_xor(sq, off); }
        const float mu  = sm * (1.0f / 128.0f);
        const float var = sq * (1.0f / 128.0f) - mu * mu;
        const float inv = rsqrtf(var + 1e-5f);
        const int g = g0 + wave;
        h1out[(size_t)g * 128 + lane]      = (x0 - mu) * inv * ln1g[lane]      + ln1b[lane];
        h1out[(size_t)g * 128 + 64 + lane] = (x1 - mu) * inv * ln1g[64 + lane] + ln1b[64 + lane];
    }
}

// ---------------------------------------------------------------------------
// K2: FFN + LN2 + mask_V. 16 rows per block, 256 blocks, 256 threads.
__global__ __launch_bounds__(256, 2)
void ffn_kernel(const float* __restrict__ h1, const bf16* __restrict__ Winb,
                const bf16* __restrict__ Woutb,
                const float* __restrict__ bin, const float* __restrict__ bout,
                const float* __restrict__ ln2g, const float* __restrict__ ln2b,
                const float* __restrict__ mask_V, float* __restrict__ out) {
    __shared__ __align__(16) bf16  a2[16 * 136];
    __shared__ __align__(16) bf16  ff[16 * 264];
    __shared__ __align__(16) float tb[16 * 132];

    const int tid  = threadIdx.x;
    const int wave = tid >> 6;
    const int lane = tid & 63;
    const int q    = lane >> 4;
    const int c15  = lane & 15;
    const int r0g  = blockIdx.x * 16;

    // stage h1 rows -> bf16 LDS
#pragma unroll
    for (int it = 0; it < 2; ++it) {
        const int idx = it * 256 + tid;      // 0..511 float4s
        const int row = idx >> 5;
        const int c4  = idx & 31;
        const float4 v = *(const float4*)(h1 + (size_t)(r0g + row) * 128 + c4 * 4);
        uint2 w;
        w.x = cvt_pk_bf16(v.x, v.y);
        w.y = cvt_pk_bf16(v.z, v.w);
        *(uint2*)(a2 + row * 136 + c4 * 4) = w;
    }

    f32x4 zero = {0.f, 0.f, 0.f, 0.f};
    f32x4 accB[2]; accB[0] = zero; accB[1] = zero;

    for (int p = 0; p < 2; ++p) {
        __syncthreads();
        // GEMM-a: [16,128] @ Win^T half -> gelu -> ff[16,256]
        f32x4 accA[4];
#pragma unroll
        for (int i = 0; i < 4; ++i) accA[i] = zero;
        __builtin_amdgcn_s_setprio(1);
#pragma unroll
        for (int s = 0; s < 4; ++s) {
            bf16x8 af = *(const bf16x8*)(a2 + c15 * 136 + s * 32 + q * 8);
#pragma unroll
            for (int nt = 0; nt < 4; ++nt) {
                const int n = p * 256 + wave * 64 + nt * 16 + c15;
                bf16x8 wb = *(const bf16x8*)(Winb + (size_t)n * 128 + s * 32 + q * 8);
                accA[nt] = mfma16(af, wb, accA[nt]);
            }
        }
        __builtin_amdgcn_s_setprio(0);
#pragma unroll
        for (int nt = 0; nt < 4; ++nt) {
            const int colL = wave * 64 + nt * 16 + c15;
            const float bb = bin[p * 256 + colL];
#pragma unroll
            for (int r = 0; r < 4; ++r) {
                const int row = q * 4 + r;
                ff[row * 264 + colL] = f2bf(gelu_exact(accA[nt][r] + bb));
            }
        }
        __syncthreads();
        // GEMM-b: ff[16,256] @ Wout^T half -> accB
        __builtin_amdgcn_s_setprio(1);
#pragma unroll
        for (int s = 0; s < 8; ++s) {
            bf16x8 af = *(const bf16x8*)(ff + c15 * 264 + s * 32 + q * 8);
#pragma unroll
            for (int nt = 0; nt < 2; ++nt) {
                const int n = wave * 32 + nt * 16 + c15;
                bf16x8 wb = *(const bf16x8*)(Woutb + (size_t)n * 512 + p * 256 + s * 32 + q * 8);
                accB[nt] = mfma16(af, wb, accB[nt]);
            }
        }
        __builtin_amdgcn_s_setprio(0);
    }
    // residual + bias -> tb
#pragma unroll
    for (int nt = 0; nt < 2; ++nt) {
        const int col = wave * 32 + nt * 16 + c15;
        const float bb = bout[col];
#pragma unroll
        for (int r = 0; r < 4; ++r) {
            const int row = q * 4 + r;
            tb[row * 132 + col] = accB[nt][r] + bb + h1[(size_t)(r0g + row) * 128 + col];
        }
    }
    __syncthreads();
    // LN2 + mask: wave w handles rows 4w..4w+3
#pragma unroll
    for (int rr = 0; rr < 4; ++rr) {
        const int row = wave * 4 + rr;
        const float x0 = tb[row * 132 + lane];
        const float x1 = tb[row * 132 + 64 + lane];
        float sm = x0 + x1, sq = x0 * x0 + x1 * x1;
#pragma unroll
        for (int off = 1; off < 64; off <<= 1) { sm += __shfl_xor(sm, off); sq += __shfl_xor(sq, off); }
        const float mu  = sm * (1.0f / 128.0f);
        const float var = sq * (1.0f / 128.0f) - mu * mu;
        const float inv = rsqrtf(var + 1e-5f);
        const int g = r0g + row;
        const float mv = mask_V[g];
        out[(size_t)g * 128 + lane]      = mv * ((x0 - mu) * inv * ln2g[lane]      + ln2b[lane]);
        out[(size_t)g * 128 + 64 + lane] = mv * ((x1 - mu) * inv * ln2g[64 + lane] + ln2b[64 + lane]);
    }
}

// ---------------------------------------------------------------------------
extern "C" void kernel_launch(void* const* d_in, const int* in_sizes, int n_in,
                              void* d_out, int out_size, void* d_ws, size_t ws_size,
                              hipStream_t stream) {
    const float* h_V         = (const float*)d_in[0];
    const float* h_E         = (const float*)d_in[1];
    const float* mask_V      = (const float*)d_in[2];
    const float* mask_attend = (const float*)d_in[3];
    const float* W1w  = (const float*)d_in[4];
    const float* W1bb = (const float*)d_in[5];
    const float* W2w  = (const float*)d_in[6];
    const float* W2bb = (const float*)d_in[7];
    const float* W3w  = (const float*)d_in[8];
    const float* W3bb = (const float*)d_in[9];
    const float* ln1g = (const float*)d_in[10];
    const float* ln1b = (const float*)d_in[11];
    const float* ln2g = (const float*)d_in[12];
    const float* ln2b = (const float*)d_in[13];
    const float* Winw  = (const float*)d_in[14];
    const float* Winbb = (const float*)d_in[15];
    const float* Woutw  = (const float*)d_in[16];
    const float* Woutbb = (const float*)d_in[17];

    bf16* wsb   = (bf16*)d_ws;
    bf16* W1c   = wsb;
    bf16* W2c   = wsb + WS_W2;
    bf16* W3c   = wsb + WS_W3;
    bf16* Winc  = wsb + WS_WIN;
    bf16* Woutc = wsb + WS_WOUT;
    float* h1   = (float*)((char*)d_ws + WS_H1_BYTES);

    convert_weights<<<896, 256, 0, stream>>>(W1w, W2w, W3w, Winw, Woutw, wsb);
    msg_kernel<<<2048, 256, 0, stream>>>(h_V, h_E, mask_attend, W1c, W2c, W3c,
                                         W1bb, W2bb, W3bb, ln1g, ln1b, h1);
    ffn_kernel<<<256, 256, 0, stream>>>(h1, Winc, Woutc, Winbb, Woutbb,
                                        ln2g, ln2b, mask_V, (float*)d_out);
}